// Round 15
// baseline (6838.869 us; speedup 1.0000x reference)
//
#include <hip/hip_runtime.h>
#include <hip/hip_bf16.h>

typedef __bf16 bf16x8 __attribute__((ext_vector_type(8)));
typedef float  f32x4  __attribute__((ext_vector_type(4)));

#define MFMA16(a, b, c) __builtin_amdgcn_mfma_f32_16x16x32_bf16((a), (b), (c), 0, 0, 0)

static constexpr int Bz = 64, Tz = 512, Dz = 512, Hz = 1024;
static constexpr int NWG0 = 128;
static constexpr int NWGT = 256;
static constexpr int NJ   = 8;

// k-major weight LDS (r14 layout, verified): elem = kk*1024 + c*32 + ((sub*8)^(((c>>2)&3)*8))
static constexpr size_t WT_BYTES  = 131072;          // 64K bf16
static constexpr size_t ZACC_OFF  = WT_BYTES;        // f32 partials, off-diagonal [12][2][64] f32x4
static constexpr size_t LDS_BYTES = WT_BYTES + 24576;   // 155648 < 160K

// ws layout, bf16 elements
static constexpr size_t N_W0X = 4096ull * 512;
static constexpr size_t N_W0H = 4096ull * 1024;
static constexpr size_t N_W1  = 4096ull * 2048;
static constexpr size_t N_Y0  = 64ull * 512 * 1024;
static constexpr size_t N_X   = 64ull * 512 * 512;
static constexpr size_t OFF_W0XH = 0;
static constexpr size_t OFF_W0XL = OFF_W0XH + N_W0X;
static constexpr size_t OFF_W0H  = OFF_W0XL + N_W0X;
static constexpr size_t OFF_W1   = OFF_W0H  + N_W0H;
static constexpr size_t OFF_Y0   = OFF_W1   + N_W1;
static constexpr size_t FLAGS_BYTE = (((OFF_Y0 + N_Y0) * 2) + 255) & ~(size_t)255;
static constexpr size_t H1S_BYTE   = FLAGS_BYTE + 4096;
static constexpr size_t WS_NEED    = H1S_BYTE + N_Y0 * 2;
static constexpr size_t XHI_BYTE   = H1S_BYTE + N_Y0 * 2;
static constexpr size_t XLO_BYTE   = XHI_BYTE + N_X * 2;
static constexpr size_t WS_NEED_X  = XLO_BYTE + N_X * 2;

static constexpr int STEP_ELEMS = 65536;

__device__ __forceinline__ float sigm(float x) { return 1.0f / (1.0f + __expf(-x)); }

__device__ __forceinline__ void st_agent_u32(void* p, unsigned v)
{ __hip_atomic_store((unsigned*)p, v, __ATOMIC_RELAXED, __HIP_MEMORY_SCOPE_AGENT); }
__device__ __forceinline__ void st_agent_f32(float* p, float v)
{ __hip_atomic_store(p, v, __ATOMIC_RELAXED, __HIP_MEMORY_SCOPE_AGENT); }

// off-diagonal partial slot for (writer wave k, M-tile m), m != k
__device__ __forceinline__ int zslot(int k, int m) { return k * 3 + (m > k ? m - 1 : m); }

// ---------------- prep (unchanged) ----------------
extern "C" __global__ void prep_split(const float* __restrict__ x,
                                      const float* __restrict__ W0,
                                      const float* __restrict__ W1,
                                      __bf16* __restrict__ ws,
                                      __bf16* __restrict__ xhi,
                                      __bf16* __restrict__ xlo)
{
    if (blockIdx.x == 0)
        for (int i = threadIdx.x; i < 1024; i += 256)
            ((unsigned*)((char*)ws + FLAGS_BYTE))[i] = 0u;

    __bf16* w0xh = ws + OFF_W0XH;
    __bf16* w0xl = ws + OFF_W0XL;
    __bf16* w0h  = ws + OFF_W0H;
    __bf16* w1c  = ws + OFF_W1;
    const size_t ntot = N_W0X + N_W0H + N_W1;
    const size_t stride = (size_t)gridDim.x * blockDim.x;
    for (size_t idx = (size_t)blockIdx.x * blockDim.x + threadIdx.x;
         idx < ntot; idx += stride) {
        if (idx < N_W0X) {
            size_t r = idx >> 9, c = idx & 511;
            float w = W0[r * 1536 + c];
            __bf16 hi = (__bf16)w;
            w0xh[idx] = hi;
            w0xl[idx] = (__bf16)(w - (float)hi);
        } else if (idx < N_W0X + N_W0H) {
            size_t i = idx - N_W0X;
            size_t r = i >> 10, c = i & 1023;
            w0h[i] = (__bf16)W0[r * 1536 + 512 + c];
        } else {
            size_t i = idx - N_W0X - N_W0H;
            w1c[i] = (__bf16)W1[i];
        }
    }
    if (xhi) {
        for (size_t idx = (size_t)blockIdx.x * blockDim.x + threadIdx.x;
             idx < N_X; idx += stride) {
            float v = x[idx];
            __bf16 hi = (__bf16)v;
            xhi[idx] = hi;
            xlo[idx] = (__bf16)(v - (float)hi);
        }
    }
}

// ---------------- sync ----------------
__device__ __forceinline__ void wait_chunk32(const unsigned* flags, int base, unsigned target)
{
    const unsigned* p = flags + base + (threadIdx.x & 31);
    for (;;) {
        unsigned v = __hip_atomic_load(p, __ATOMIC_RELAXED, __HIP_MEMORY_SCOPE_AGENT);
        if (__all(v >= target)) break;
        __builtin_amdgcn_s_sleep(1);
    }
    asm volatile("" ::: "memory");
}

// x-quarter GEMM, pre-split (4 kk, all 4 M-tiles; one w-read feeds 4 MFMAs)
__device__ __forceinline__ void zxq_ps(f32x4 (&acc)[4][2], size_t tofs,
    const __bf16* const (&xph)[4], const __bf16* const (&xpl)[4],
    const __bf16* wxh0, const __bf16* wxl0, const __bf16* wxh1, const __bf16* wxl1)
{
#pragma unroll
    for (int kkL = 0; kkL < 4; ++kkL) {
        bf16x8 wh0 = *(const bf16x8*)(wxh0 + kkL * 1024);
        bf16x8 wl0 = *(const bf16x8*)(wxl0 + kkL * 1024);
        bf16x8 wh1 = *(const bf16x8*)(wxh1 + kkL * 1024);
        bf16x8 wl1 = *(const bf16x8*)(wxl1 + kkL * 1024);
#pragma unroll
        for (int m = 0; m < 4; ++m) {
            bf16x8 ahi = *(const bf16x8*)(xph[m] + tofs + kkL * 32);
            bf16x8 alo = *(const bf16x8*)(xpl[m] + tofs + kkL * 32);
            acc[m][0] = MFMA16(ahi, wh0, acc[m][0]);
            acc[m][0] = MFMA16(alo, wh0, acc[m][0]);
            acc[m][0] = MFMA16(ahi, wl0, acc[m][0]);
            acc[m][1] = MFMA16(ahi, wh1, acc[m][1]);
            acc[m][1] = MFMA16(alo, wh1, acc[m][1]);
            acc[m][1] = MFMA16(ahi, wl1, acc[m][1]);
        }
    }
}

__device__ __forceinline__ void zxq_fb(f32x4 (&acc)[4][2], size_t tofs,
    const float* const (&xpf)[4],
    const __bf16* wxh0, const __bf16* wxl0, const __bf16* wxh1, const __bf16* wxl1)
{
#pragma unroll
    for (int kkL = 0; kkL < 4; ++kkL) {
        bf16x8 wh0 = *(const bf16x8*)(wxh0 + kkL * 1024);
        bf16x8 wl0 = *(const bf16x8*)(wxl0 + kkL * 1024);
        bf16x8 wh1 = *(const bf16x8*)(wxh1 + kkL * 1024);
        bf16x8 wl1 = *(const bf16x8*)(wxl1 + kkL * 1024);
#pragma unroll
        for (int m = 0; m < 4; ++m) {
            f32x4 va = *(const f32x4*)(xpf[m] + tofs + kkL * 32);
            f32x4 vb = *(const f32x4*)(xpf[m] + tofs + kkL * 32 + 4);
            bf16x8 ahi, alo;
#pragma unroll
            for (int e = 0; e < 4; ++e) {
                float v = va[e]; __bf16 h1 = (__bf16)v;
                ahi[e] = h1; alo[e] = (__bf16)(v - (float)h1);
                float w = vb[e]; __bf16 h2 = (__bf16)w;
                ahi[4 + e] = h2; alo[4 + e] = (__bf16)(w - (float)h2);
            }
            acc[m][0] = MFMA16(ahi, wh0, acc[m][0]);
            acc[m][0] = MFMA16(alo, wh0, acc[m][0]);
            acc[m][0] = MFMA16(ahi, wl0, acc[m][0]);
            acc[m][1] = MFMA16(ahi, wh1, acc[m][1]);
            acc[m][1] = MFMA16(alo, wh1, acc[m][1]);
            acc[m][1] = MFMA16(ahi, wl1, acc[m][1]);
        }
    }
}

// cross-wave K-reduce: write off-diagonal partials, barrier, sum own M-tile
__device__ __forceinline__ void kreduce(f32x4 (&acc)[4][2], float* zacc,
                                        int wave, int lane, const float* bv,
                                        f32x4& za, f32x4& zb)
{
#pragma unroll
    for (int m = 0; m < 4; ++m) {
        if (m == wave) continue;
        int sl = zslot(wave, m);
        *(f32x4*)(zacc + ((sl * 2 + 0) * 64 + lane) * 4) = acc[m][0];
        *(f32x4*)(zacc + ((sl * 2 + 1) * 64 + lane) * 4) = acc[m][1];
    }
    __syncthreads();
    za = acc[wave][0];
    zb = acc[wave][1];
#pragma unroll
    for (int k = 0; k < 4; ++k) {
        if (k == wave) continue;
        int sl = zslot(k, wave);
        za += *(const f32x4*)(zacc + ((sl * 2 + 0) * 64 + lane) * 4);
        zb += *(const f32x4*)(zacc + ((sl * 2 + 1) * 64 + lane) * 4);
    }
#pragma unroll
    for (int e = 0; e < 4; ++e) { za[e] += bv[0]; zb[e] += bv[1]; }
}

// gates + blocked full-line store (verbatim r12)
template <bool F32OUT>
__device__ __forceinline__ void gates_store(
    f32x4 za, f32x4 zb, float* cs, int lane, int l15, int rowBase,
    unsigned* yline, float* yf32, size_t rowStride)
{
    f32x4 pa, pb;
#pragma unroll
    for (int e = 0; e < 4; ++e) { pa[e] = __shfl_xor(za[e], 8, 64); pb[e] = __shfl_xor(zb[e], 8, 64); }
    const bool hi = (l15 & 8) != 0;
    int p01[2];
#pragma unroll
    for (int k2 = 0; k2 < 2; ++k2) {
        float zi, zf, zo, zg;
        if (hi) { zi = pa[2 + k2]; zf = za[2 + k2]; zo = pb[2 + k2]; zg = zb[2 + k2]; }
        else    { zi = za[k2];     zf = pa[k2];     zo = zb[k2];     zg = pb[k2];     }
        float cn = sigm(zf) * cs[k2] + sigm(zi) * tanhf(zg);
        float hn = sigm(zo) * tanhf(cn);
        cs[k2] = cn;
        if (F32OUT) {
            int b = rowBase + (hi ? 2 : 0) + k2;
            st_agent_f32(&yf32[(size_t)b * rowStride], hn);
        }
        __bf16 hb = (__bf16)hn;
        unsigned bits = (unsigned)__builtin_bit_cast(unsigned short, hb);
        unsigned par  = __shfl_down(bits, 1, 64);
        p01[k2] = (int)(bits | (par << 16));
    }
    if (yline) {
        int r    = lane >> 2;
        int srcl = ((r >> 2) << 4) | (((r >> 1) & 1) << 3) | ((lane & 3) << 1);
        unsigned v0 = (unsigned)__builtin_amdgcn_ds_bpermute(srcl * 4, p01[0]);
        unsigned v1 = (unsigned)__builtin_amdgcn_ds_bpermute(srcl * 4, p01[1]);
        st_agent_u32(yline + lane, (r & 1) ? v1 : v0);
    }
}

// ---------------- layer 0 (K-split waves) ----------------
__device__ __forceinline__ void layer0(
    const float* __restrict__ x,
    const __bf16* __restrict__ xhi, const __bf16* __restrict__ xlo,
    const __bf16* __restrict__ w0xh, const __bf16* __restrict__ w0xl,
    const __bf16* __restrict__ w0h,  const float* __restrict__ b0,
    __bf16* y0, __bf16* wtile, float* zacc, unsigned* flags0)
{
    const int tid  = threadIdx.x;
    const int wave = tid >> 6, lane = tid & 63, l15 = lane & 15, lg = lane >> 4;
    const int wg   = blockIdx.x;
    const int j0   = wg * NJ;

    // ---- stage weights kk-major (r14, verified) ----
    __bf16* sWXH = wtile;            // [16][1024]
    __bf16* sWXL = wtile + 16384;
    __bf16* sWH  = wtile + 32768;    // [32][1024]
    for (int idx = tid; idx < 32 * (Dz / 8); idx += 256) {
        int r = idx >> 6, k8 = idx & 63;
        int kk = k8 >> 2, sub = k8 & 3;
        int dst = kk * 1024 + r * 32 + ((sub * 8) ^ (((r >> 2) & 3) * 8));
        size_t grow = (size_t)((r >> 3) * Hz + j0 + (r & 7));
        *(bf16x8*)(sWXH + dst) = *(const bf16x8*)(w0xh + grow * Dz + k8 * 8);
        *(bf16x8*)(sWXL + dst) = *(const bf16x8*)(w0xl + grow * Dz + k8 * 8);
    }
    for (int idx = tid; idx < 32 * (Hz / 8); idx += 256) {
        int r = idx >> 7, k8 = idx & 127;
        int kk = k8 >> 2, sub = k8 & 3;
        int dst = kk * 1024 + r * 32 + ((sub * 8) ^ (((r >> 2) & 3) * 8));
        size_t grow = (size_t)((r >> 3) * Hz + j0 + (r & 7));
        *(bf16x8*)(sWH + dst) = *(const bf16x8*)(w0h + grow * Hz + k8 * 8);
    }
    __syncthreads();

    // this wave's K-quarter weight bases
    const __bf16* wxh[2]; const __bf16* wxl[2]; const __bf16* whp[2]; float bv[2];
#pragma unroll
    for (int tn = 0; tn < 2; ++tn) {
        int c = tn * 16 + l15;
        int lofs = c * 32 + ((lg * 8) ^ (((c >> 2) & 3) * 8));
        wxh[tn] = sWXH + lofs + wave * 4096;     // x-quarter: 4 kk
        wxl[tn] = sWXL + lofs + wave * 4096;
        whp[tn] = sWH  + lofs + wave * 8192;     // h-quarter: 8 kk
        bv[tn]  = b0[(c >> 3) * Hz + j0 + (c & 7)];
    }
    // A-pointers per M-tile
    const __bf16* xph[4]; const __bf16* xpl[4]; const float* xpf[4]; const __bf16* hpm[4];
#pragma unroll
    for (int m = 0; m < 4; ++m) {
        size_t rofs = (size_t)(m * 16 + l15) * Tz * Dz + wave * 128 + lg * 8;
        xph[m] = xhi ? xhi + rofs : nullptr;
        xpl[m] = xlo ? xlo + rofs : nullptr;
        xpf[m] = x + rofs;
        hpm[m] = y0 + m * 128 + l15 * 8 + lg * 512 + wave * 8 * 2048;
    }

    unsigned* myflag = flags0 + wg;
    float cs[2] = {0.f, 0.f};

    f32x4 acc[4][2];
#pragma unroll
    for (int m = 0; m < 4; ++m) { acc[m][0] = f32x4{0,0,0,0}; acc[m][1] = f32x4{0,0,0,0}; }
    if (xhi) zxq_ps(acc, 0, xph, xpl, wxh[0], wxl[0], wxh[1], wxl[1]);
    else     zxq_fb(acc, 0, xpf,      wxh[0], wxl[0], wxh[1], wxl[1]);

    for (int s = 0; s < Tz; ++s) {
        if (s > 0) {
            wait_chunk32(flags0, 32 * wave, (unsigned)s);   // only THIS quarter's producers
            const size_t hofs = (size_t)(s - 1) * STEP_ELEMS;
#pragma unroll
            for (int kkL = 0; kkL < 8; ++kkL) {
                bf16x8 w0v = *(const bf16x8*)(whp[0] + kkL * 1024);
                bf16x8 w1v = *(const bf16x8*)(whp[1] + kkL * 1024);
#pragma unroll
                for (int m = 0; m < 4; ++m) {
                    bf16x8 a = *(const bf16x8*)(hpm[m] + hofs + kkL * 2048);
                    acc[m][0] = MFMA16(a, w0v, acc[m][0]);
                    acc[m][1] = MFMA16(a, w1v, acc[m][1]);
                }
            }
        }
        f32x4 za, zb;
        kreduce(acc, zacc, wave, lane, bv, za, zb);

        unsigned* yline = (unsigned*)y0 + (size_t)s * (STEP_ELEMS / 2) + wg * 256 + wave * 64;
        gates_store<false>(za, zb, cs, lane, l15, wave * 16 + lg * 4, yline, nullptr, 0);

        asm volatile("s_waitcnt vmcnt(0)" ::: "memory");
        __syncthreads();
        if (tid == 0) st_agent_u32(myflag, (unsigned)(s + 1));

        if (s < Tz - 1) {
#pragma unroll
            for (int m = 0; m < 4; ++m) { acc[m][0] = f32x4{0,0,0,0}; acc[m][1] = f32x4{0,0,0,0}; }
            if (xhi) zxq_ps(acc, (size_t)(s + 1) * Dz, xph, xpl, wxh[0], wxl[0], wxh[1], wxl[1]);
            else     zxq_fb(acc, (size_t)(s + 1) * Dz, xpf,      wxh[0], wxl[0], wxh[1], wxl[1]);
        }
    }
}

// ---------------- layer 1 (K-split waves) ----------------
__device__ __forceinline__ void layer1(
    const __bf16* __restrict__ y0, const __bf16* __restrict__ w1c,
    const float* __restrict__ b1, float* out, __bf16* h1s,
    __bf16* wtile, float* zacc, unsigned* flags0, unsigned* flags1)
{
    const int tid  = threadIdx.x;
    const int wave = tid >> 6, lane = tid & 63, l15 = lane & 15, lg = lane >> 4;
    const int wg   = blockIdx.x - NWG0;
    const int j0   = wg * NJ;

    __bf16* sWX = wtile;             // [32][1024]
    __bf16* sWH = wtile + 32768;
    for (int idx = tid; idx < 32 * (Hz / 8); idx += 256) {
        int r = idx >> 7, k8 = idx & 127;
        int kk = k8 >> 2, sub = k8 & 3;
        int dst = kk * 1024 + r * 32 + ((sub * 8) ^ (((r >> 2) & 3) * 8));
        size_t grow = (size_t)((r >> 3) * Hz + j0 + (r & 7));
        const __bf16* srow = w1c + grow * 2048;
        *(bf16x8*)(sWX + dst) = *(const bf16x8*)(srow + k8 * 8);
        *(bf16x8*)(sWH + dst) = *(const bf16x8*)(srow + 1024 + k8 * 8);
    }
    __syncthreads();

    const __bf16* wxp[2]; const __bf16* whp[2]; float bv[2];
#pragma unroll
    for (int tn = 0; tn < 2; ++tn) {
        int c = tn * 16 + l15;
        int lofs = c * 32 + ((lg * 8) ^ (((c >> 2) & 3) * 8));
        wxp[tn] = sWX + lofs + wave * 8192;
        whp[tn] = sWH + lofs + wave * 8192;
        bv[tn]  = b1[(c >> 3) * Hz + j0 + (c & 7)];
    }
    const __bf16* xp0[4]; const __bf16* hs0[4]; const float* hpf[4];
#pragma unroll
    for (int m = 0; m < 4; ++m) {
        xp0[m] = y0 + m * 128 + l15 * 8 + lg * 512 + wave * 8 * 2048;
        hs0[m] = h1s ? h1s + m * 128 + l15 * 8 + lg * 512 + wave * 8 * 2048 : nullptr;
        hpf[m] = out + (size_t)(m * 16 + l15) * Tz * Hz + lg * 8 + wave * 256;
    }

    unsigned* myflag = flags1 + wg;
    float cs[2] = {0.f, 0.f};

    for (int s = 1; s <= Tz; ++s) {
        const int t = s - 1;
        f32x4 acc[4][2];
#pragma unroll
        for (int m = 0; m < 4; ++m) { acc[m][0] = f32x4{0,0,0,0}; acc[m][1] = f32x4{0,0,0,0}; }

        // h-part first (own-layer flags, ~already set)
        if (t > 0) {
            wait_chunk32(flags1, 32 * wave, (unsigned)(s - 1));
            if (h1s) {
                const size_t hofs = (size_t)(t - 1) * STEP_ELEMS;
#pragma unroll
                for (int kkL = 0; kkL < 8; ++kkL) {
                    bf16x8 w0v = *(const bf16x8*)(whp[0] + kkL * 1024);
                    bf16x8 w1v = *(const bf16x8*)(whp[1] + kkL * 1024);
#pragma unroll
                    for (int m = 0; m < 4; ++m) {
                        bf16x8 a = *(const bf16x8*)(hs0[m] + hofs + kkL * 2048);
                        acc[m][0] = MFMA16(a, w0v, acc[m][0]);
                        acc[m][1] = MFMA16(a, w1v, acc[m][1]);
                    }
                }
            } else {
                const size_t hofs = (size_t)(t - 1) * Hz;
#pragma unroll
                for (int kkL = 0; kkL < 8; ++kkL) {
                    bf16x8 w0v = *(const bf16x8*)(whp[0] + kkL * 1024);
                    bf16x8 w1v = *(const bf16x8*)(whp[1] + kkL * 1024);
#pragma unroll
                    for (int m = 0; m < 4; ++m) {
                        f32x4 va = *(const f32x4*)(hpf[m] + hofs + kkL * 32);
                        f32x4 vb = *(const f32x4*)(hpf[m] + hofs + kkL * 32 + 4);
                        bf16x8 a;
#pragma unroll
                        for (int e = 0; e < 4; ++e) { a[e] = (__bf16)va[e]; a[4 + e] = (__bf16)vb[e]; }
                        acc[m][0] = MFMA16(a, w0v, acc[m][0]);
                        acc[m][1] = MFMA16(a, w1v, acc[m][1]);
                    }
                }
            }
        }
        // x-part: consume y0[s-1] (this wave's K-quarter producers only)
        {
            wait_chunk32(flags0, 32 * wave, (unsigned)s);
            const size_t xofs = (size_t)t * STEP_ELEMS;
#pragma unroll
            for (int kkL = 0; kkL < 8; ++kkL) {
                bf16x8 w0v = *(const bf16x8*)(wxp[0] + kkL * 1024);
                bf16x8 w1v = *(const bf16x8*)(wxp[1] + kkL * 1024);
#pragma unroll
                for (int m = 0; m < 4; ++m) {
                    bf16x8 a = *(const bf16x8*)(xp0[m] + xofs + kkL * 2048);
                    acc[m][0] = MFMA16(a, w0v, acc[m][0]);
                    acc[m][1] = MFMA16(a, w1v, acc[m][1]);
                }
            }
        }

        f32x4 za, zb;
        kreduce(acc, zacc, wave, lane, bv, za, zb);

        unsigned* hline = h1s ? (unsigned*)h1s + (size_t)t * (STEP_ELEMS / 2) + wg * 256 + wave * 64
                              : nullptr;
        gates_store<true>(za, zb, cs, lane, l15, wave * 16 + lg * 4,
                          hline, out + (size_t)t * Hz + j0 + (l15 & 7), (size_t)Tz * Hz);

        asm volatile("s_waitcnt vmcnt(0)" ::: "memory");
        __syncthreads();
        if (tid == 0 && s < Tz) st_agent_u32(myflag, (unsigned)s);
    }
}

extern "C" __global__ void __launch_bounds__(256, 1)
lstm2(const float* __restrict__ x,
      const float* __restrict__ b0,
      const float* __restrict__ b1,
      __bf16* ws,
      float* out,
      __bf16* h1s,
      const __bf16* __restrict__ xhi,
      const __bf16* __restrict__ xlo)
{
    extern __shared__ char lds_raw[];
    __bf16* wtile = (__bf16*)lds_raw;
    float*  zacc  = (float*)(lds_raw + ZACC_OFF);
    unsigned* flags0 = (unsigned*)((char*)ws + FLAGS_BYTE);
    unsigned* flags1 = (unsigned*)((char*)ws + FLAGS_BYTE + 2048);

    if (blockIdx.x < NWG0)
        layer0(x, xhi, xlo, ws + OFF_W0XH, ws + OFF_W0XL, ws + OFF_W0H, b0,
               ws + OFF_Y0, wtile, zacc, flags0);
    else
        layer1(ws + OFF_Y0, ws + OFF_W1, b1, out, h1s, wtile, zacc, flags0, flags1);
}

extern "C" void kernel_launch(void* const* d_in, const int* in_sizes, int n_in,
                              void* d_out, int out_size, void* d_ws, size_t ws_size,
                              hipStream_t stream)
{
    const float* x  = (const float*)d_in[0];
    const float* W0 = (const float*)d_in[1];
    const float* b0 = (const float*)d_in[2];
    const float* W1 = (const float*)d_in[3];
    const float* b1 = (const float*)d_in[4];
    float* out = (float*)d_out;
    __bf16* ws = (__bf16*)d_ws;
    __bf16* h1s = (ws_size >= WS_NEED)   ? (__bf16*)((char*)ws + H1S_BYTE) : nullptr;
    __bf16* xhi = (ws_size >= WS_NEED_X) ? (__bf16*)((char*)ws + XHI_BYTE) : nullptr;
    __bf16* xlo = (ws_size >= WS_NEED_X) ? (__bf16*)((char*)ws + XLO_BYTE) : nullptr;

    (void)hipFuncSetAttribute((const void*)lstm2,
                        hipFuncAttributeMaxDynamicSharedMemorySize, (int)LDS_BYTES);

    hipLaunchKernelGGL(prep_split, dim3(2048), dim3(256), 0, stream, x, W0, W1, ws, xhi, xlo);

    const __bf16* xhic = xhi; const __bf16* xloc = xlo;
    void* args[] = { (void*)&x, (void*)&b0, (void*)&b1, (void*)&ws, (void*)&out,
                     (void*)&h1s, (void*)&xhic, (void*)&xloc };
    (void)hipLaunchCooperativeKernel(reinterpret_cast<void*>(lstm2),
                               dim3(NWGT), dim3(256), args, LDS_BYTES, stream);
}